// Round 10
// baseline (204.748 us; speedup 1.0000x reference)
//
#include <hip/hip_runtime.h>
#include <hip/hip_bf16.h>
#include <cstdint>

// B=8 T=4 N1=1024 N2=64 DIM=1024 HEADS=8 DHEAD=64 INNER=512
// BT = 32, NR = N1+N2 = 1088, concat rows = 34816
// Pipeline: {weight transpose | LN} fused -> kv GEMM -> q GEMM -> attention -> out GEMM
// (kv/q kept as SEPARATE launches: in-kernel fusion cost 16 VGPR -> -9% occupancy, R9)

typedef __bf16 bf16x8 __attribute__((ext_vector_type(8)));
typedef __bf16 bf16x4 __attribute__((ext_vector_type(4)));
typedef float  f32x4  __attribute__((ext_vector_type(4)));

__device__ __forceinline__ void gload_lds16(const void* g, void* l) {
    __builtin_amdgcn_global_load_lds(
        (const __attribute__((address_space(1))) unsigned int*)g,
        (__attribute__((address_space(3))) unsigned int*)l, 16, 0, 0);
}

// ---------------------------------------------------------------- prep: transpose + LN
// Blocks [0,2048): weight transpose f32 [K][N] -> bf16 [N][K].
//   [0,512) Wq (x0.125 folded); [512,1536) Wkv; [1536,2048) Wout.
// Blocks [2048, 2048+34816): LN rows -> concat; latent rows also -> latln (compact).
__global__ __launch_bounds__(256) void prep_kernel(
    const float* __restrict__ Wq, const float* __restrict__ Wkv,
    const float* __restrict__ Wout,
    __bf16* __restrict__ WqT, __bf16* __restrict__ WkvT, __bf16* __restrict__ WoutT,
    const float* __restrict__ x, const float* __restrict__ lat,
    const float* __restrict__ g_m, const float* __restrict__ b_m,
    const float* __restrict__ g_l, const float* __restrict__ b_l,
    __bf16* __restrict__ concat, __bf16* __restrict__ latln) {
    __shared__ float tile[32][33];
    __shared__ float ss[4], qq[4];
    int id = blockIdx.x;
    if (id < 2048) {
        // ---------- weight transpose ----------
        const float* src; __bf16* dst; int N; int bx, by; float wscale;
        if (id < 512)       { src = Wq;   dst = WqT;   N = 512;
                              bx = id & 15;  by = id >> 4;  wscale = 0.125f; }
        else if (id < 1536) { int i = id - 512;  src = Wkv;  dst = WkvT;  N = 1024;
                              bx = i & 31;  by = i >> 5;  wscale = 1.0f; }
        else                { int i = id - 1536; src = Wout; dst = WoutT; N = 1024;
                              bx = i & 31;  by = i >> 5;  wscale = 1.0f; }
        int K = (id < 1536) ? 1024 : 512;
        int n0 = bx * 32, k0 = by * 32;
        int tx = threadIdx.x & 31, ty = threadIdx.x >> 5;   // 32x8
#pragma unroll
        for (int i = 0; i < 4; ++i)
            tile[ty + i * 8][tx] = src[(size_t)(k0 + ty + i * 8) * N + n0 + tx];
        __syncthreads();
#pragma unroll
        for (int i = 0; i < 4; ++i)
            dst[(size_t)(n0 + ty + i * 8) * K + k0 + tx] =
                (__bf16)(tile[tx][ty + i * 8] * wscale);
        return;
    }
    // ---------- layernorm ----------
    int row = id - 2048;                // 0..34815
    int bt  = row / 1088;
    int r   = row - bt * 1088;
    const float *src, *g, *b;
    if (r < 1024) { src = x   + ((size_t)(bt * 1024 + r) << 10);        g = g_m; b = b_m; }
    else          { src = lat + ((size_t)(bt * 64 + (r - 1024)) << 10); g = g_l; b = b_l; }
    int t = threadIdx.x;
    float4 v = ((const float4*)src)[t];
    float s = v.x + v.y + v.z + v.w;
    float q = v.x * v.x + v.y * v.y + v.z * v.z + v.w * v.w;
#pragma unroll
    for (int m = 1; m < 64; m <<= 1) { s += __shfl_xor(s, m); q += __shfl_xor(q, m); }
    int w = t >> 6;
    if ((t & 63) == 0) { ss[w] = s; qq[w] = q; }
    __syncthreads();
    s = ss[0] + ss[1] + ss[2] + ss[3];
    q = qq[0] + qq[1] + qq[2] + qq[3];
    float mean = s * (1.0f / 1024.0f);
    float var  = q * (1.0f / 1024.0f) - mean * mean;
    float rstd = rsqrtf(var + 1e-5f);
    float4 gv = ((const float4*)g)[t];
    float4 bv = ((const float4*)b)[t];
    bf16x4 o;
    o[0] = (__bf16)((v.x - mean) * rstd * gv.x + bv.x);
    o[1] = (__bf16)((v.y - mean) * rstd * gv.y + bv.y);
    o[2] = (__bf16)((v.z - mean) * rstd * gv.z + bv.z);
    o[3] = (__bf16)((v.w - mean) * rstd * gv.w + bv.w);
    *(bf16x4*)(concat + ((size_t)row << 10) + t * 4) = o;
    if (r >= 1024)
        *(bf16x4*)(latln + ((size_t)(bt * 64 + (r - 1024)) << 10) + t * 4) = o;
}

// ---------------------------------------------------------------- GEMM 128^2 (m97-style)
// C[M][N] = A[M][K] @ Bt[N][K]^T. 256 threads (4 waves), BK=64, global_load_lds w=16,
// inverse-swizzled source column + XOR ds_read (round-3-verified: 0 conflicts, 80 VGPR).
#define BKK 64

template <bool OUT_BF16>
__global__ __launch_bounds__(256) void gemm_bf16(
    const __bf16* __restrict__ A, const __bf16* __restrict__ Bt,
    void* __restrict__ C, int M, int N, int K, float scale, int gx) {
    __shared__ __bf16 As[128 * BKK];
    __shared__ __bf16 Bs[128 * BKK];
    int tid  = threadIdx.x;
    int lane = tid & 63, wave = tid >> 6;

    int nwg = gridDim.x;
    int id  = blockIdx.x;
    int cpx = nwg >> 3;
    int swz = (id & 7) * cpx + (id >> 3);
    int bm = swz / gx, bn = swz % gx;

    int wr = (wave >> 1) * 64, wc = (wave & 1) * 64;
    int l15 = lane & 15, lh = lane >> 4;
    int srow = lane >> 3;
    int scol = ((lane & 7) ^ srow) * 8;           // inverse-swizzled source column

    const __bf16* abase[4];
    const __bf16* bbase[4];
#pragma unroll
    for (int i = 0; i < 4; ++i) {
        int r = wave * 32 + i * 8 + srow;
        abase[i] = A + (size_t)(bm * 128 + r) * K + scol;
        bbase[i] = Bt + (size_t)(bn * 128 + r) * K + scol;
    }

    f32x4 acc[4][4] = {};

    for (int k0 = 0; k0 < K; k0 += BKK) {
        __syncthreads();
#pragma unroll
        for (int i = 0; i < 4; ++i) {
            gload_lds16(abase[i] + k0, &As[(wave * 32 + i * 8) * BKK]);
            gload_lds16(bbase[i] + k0, &Bs[(wave * 32 + i * 8) * BKK]);
        }
        __syncthreads();
#pragma unroll
        for (int kk = 0; kk < BKK; kk += 32) {
            int cb = (kk + lh * 8) * 2;
            bf16x8 af[4], bfr[4];
#pragma unroll
            for (int mi = 0; mi < 4; ++mi) {
                int r = wr + mi * 16 + l15;
                af[mi] = *(const bf16x8*)((const char*)As + r * 128 + (cb ^ ((r & 7) << 4)));
            }
#pragma unroll
            for (int ni = 0; ni < 4; ++ni) {
                int r = wc + ni * 16 + l15;
                bfr[ni] = *(const bf16x8*)((const char*)Bs + r * 128 + (cb ^ ((r & 7) << 4)));
            }
#pragma unroll
            for (int mi = 0; mi < 4; ++mi)
#pragma unroll
                for (int ni = 0; ni < 4; ++ni)
                    acc[mi][ni] = __builtin_amdgcn_mfma_f32_16x16x32_bf16(
                        af[mi], bfr[ni], acc[mi][ni], 0, 0, 0);
        }
    }
    // epilogue: D row = lh*4+jj, col = l15 (m89-verified)
#pragma unroll
    for (int mi = 0; mi < 4; ++mi)
#pragma unroll
        for (int ni = 0; ni < 4; ++ni)
#pragma unroll
            for (int jj = 0; jj < 4; ++jj) {
                int row = bm * 128 + wr + mi * 16 + lh * 4 + jj;
                int col = bn * 128 + wc + ni * 16 + l15;
                float val = acc[mi][ni][jj] * scale;
                if (OUT_BF16) ((__bf16*)C)[(size_t)row * N + col] = (__bf16)val;
                else          ((float*)C)[(size_t)row * N + col]  = val;
            }
}

// ---------------------------------------------------------------- attention
__global__ __launch_bounds__(1024) void attn_kernel(
    const __bf16* __restrict__ q,    // [32][64][512], pre-scaled by 0.125
    const __bf16* __restrict__ kv,   // [32][1088][1024]  (k: cols 0..511, v: 512..1023)
    __bf16* __restrict__ o) {        // [32][64][512]
    int blk = blockIdx.x;            // 0..255
    int bt = blk >> 3, h = blk & 7;
    int tid = threadIdx.x;
    int cid  = tid >> 8;             // KV chunk 0..3
    int ctid = tid & 255;
    int wave = tid >> 6;             // 0..15
    int g    = wave & 3;             // q-row group
    int lane = tid & 63, l15 = lane & 15, lh = lane >> 4;

    __shared__ __bf16 vT[4][64 * 64];     // per-chunk [d][j] swizzled, 32 KB
    __shared__ __bf16 Pl[16][16 * 64];    // per-wave  [r][j] swizzled, 32 KB
    float* mbuf = (float*)&vT[1][0];      // [4][4][16]  (aliased, dead region)
    float* lbuf = mbuf + 256;             // [4][4][16]
    float* Osum = (float*)&Pl[0][0];      // [4][16][64]

    const __bf16* qbase = q + ((size_t)bt * 64 + g * 16) * 512 + h * 64;
    bf16x8 qf[2];
    qf[0] = *(const bf16x8*)(qbase + (size_t)l15 * 512 + lh * 8);
    qf[1] = *(const bf16x8*)(qbase + (size_t)l15 * 512 + 32 + lh * 8);

    const __bf16* kvbt = kv + (size_t)bt * 1088 * 1024;

    float m_s[4], l_s[4];
    f32x4 oacc[4];
#pragma unroll
    for (int jj = 0; jj < 4; ++jj) { m_s[jj] = -1e30f; l_s[jj] = 0.f; }
#pragma unroll
    for (int d = 0; d < 4; ++d) oacc[d] = f32x4{0.f, 0.f, 0.f, 0.f};

    for (int it = 0; it < 5; ++it) {
        int tile = it * 4 + cid;
        bool act = tile < 17;
        int j0 = tile * 64;
        __syncthreads();
        if (act) {
#pragma unroll
            for (int it2 = 0; it2 < 2; ++it2) {
                int idx = it2 * 256 + ctid;
                int j = idx >> 3, c = idx & 7;
                bf16x8 vv = *(const bf16x8*)(kvbt + (size_t)(j0 + j) * 1024 + 512 + h * 64 + c * 8);
#pragma unroll
                for (int e = 0; e < 8; ++e) {
                    int d = c * 8 + e;
                    *(__bf16*)((char*)vT[cid] + d * 128 + ((j * 2) ^ ((d & 7) << 4))) = vv[e];
                }
            }
        }
        __syncthreads();
        if (act) {
            f32x4 s[4];
            f32x4 zero = {0.f, 0.f, 0.f, 0.f};
#pragma unroll
            for (int ni = 0; ni < 4; ++ni) {
                const __bf16* kp = kvbt + (size_t)(j0 + ni * 16 + l15) * 1024 + h * 64;
                bf16x8 kf0 = *(const bf16x8*)(kp + lh * 8);
                bf16x8 kf1 = *(const bf16x8*)(kp + 32 + lh * 8);
                f32x4 t0 = __builtin_amdgcn_mfma_f32_16x16x32_bf16(qf[0], kf0, zero, 0, 0, 0);
                s[ni]    = __builtin_amdgcn_mfma_f32_16x16x32_bf16(qf[1], kf1, t0,   0, 0, 0);
            }
            float tm[4];
#pragma unroll
            for (int jj = 0; jj < 4; ++jj)
                tm[jj] = fmaxf(fmaxf(s[0][jj], s[1][jj]), fmaxf(s[2][jj], s[3][jj]));
#pragma unroll
            for (int m = 1; m < 16; m <<= 1)
#pragma unroll
                for (int jj = 0; jj < 4; ++jj) tm[jj] = fmaxf(tm[jj], __shfl_xor(tm[jj], m));
            float alpha[4];
#pragma unroll
            for (int jj = 0; jj < 4; ++jj) {
                float mn = fmaxf(m_s[jj], tm[jj]);
                alpha[jj] = __expf(m_s[jj] - mn);
                m_s[jj] = mn;
            }
            float p[4][4];
            float ts[4] = {0.f, 0.f, 0.f, 0.f};
#pragma unroll
            for (int ni = 0; ni < 4; ++ni)
#pragma unroll
                for (int jj = 0; jj < 4; ++jj) {
                    p[ni][jj] = __expf(s[ni][jj] - m_s[jj]);
                    ts[jj] += p[ni][jj];
                }
#pragma unroll
            for (int m = 1; m < 16; m <<= 1)
#pragma unroll
                for (int jj = 0; jj < 4; ++jj) ts[jj] += __shfl_xor(ts[jj], m);
#pragma unroll
            for (int jj = 0; jj < 4; ++jj) l_s[jj] = l_s[jj] * alpha[jj] + ts[jj];
#pragma unroll
            for (int d = 0; d < 4; ++d)
#pragma unroll
                for (int jj = 0; jj < 4; ++jj) oacc[d][jj] *= alpha[jj];
#pragma unroll
            for (int ni = 0; ni < 4; ++ni)
#pragma unroll
                for (int jj = 0; jj < 4; ++jj) {
                    int r = lh * 4 + jj, j = ni * 16 + l15;
                    *(__bf16*)((char*)Pl[wave] + r * 128 + ((j * 2) ^ ((r & 7) << 4))) =
                        (__bf16)p[ni][jj];
                }
        }
        __syncthreads();   // P write -> P read
        if (act) {
            bf16x8 pf[2];
            pf[0] = *(const bf16x8*)((char*)Pl[wave] + l15 * 128 + ((lh * 16)      ^ ((l15 & 7) << 4)));
            pf[1] = *(const bf16x8*)((char*)Pl[wave] + l15 * 128 + ((64 + lh * 16) ^ ((l15 & 7) << 4)));
#pragma unroll
            for (int dblk = 0; dblk < 4; ++dblk) {
                int dr = dblk * 16 + l15;
                bf16x8 vf0 = *(const bf16x8*)((char*)vT[cid] + dr * 128 + ((lh * 16)      ^ ((dr & 7) << 4)));
                bf16x8 vf1 = *(const bf16x8*)((char*)vT[cid] + dr * 128 + ((64 + lh * 16) ^ ((dr & 7) << 4)));
                oacc[dblk] = __builtin_amdgcn_mfma_f32_16x16x32_bf16(pf[0], vf0, oacc[dblk], 0, 0, 0);
                oacc[dblk] = __builtin_amdgcn_mfma_f32_16x16x32_bf16(pf[1], vf1, oacc[dblk], 0, 0, 0);
            }
        }
    }

    // -------- flash merge of 4 chunk-partials --------
    __syncthreads();
    if (l15 == 0) {
#pragma unroll
        for (int jj = 0; jj < 4; ++jj) {
            mbuf[(cid * 4 + g) * 16 + lh * 4 + jj] = m_s[jj];
            lbuf[(cid * 4 + g) * 16 + lh * 4 + jj] = l_s[jj];
        }
    }
    __syncthreads();
    float sc[4], Lsum[4];
#pragma unroll
    for (int jj = 0; jj < 4; ++jj) {
        int r = lh * 4 + jj;
        float M = mbuf[(0 * 4 + g) * 16 + r];
#pragma unroll
        for (int c = 1; c < 4; ++c) M = fmaxf(M, mbuf[(c * 4 + g) * 16 + r]);
        sc[jj] = __expf(m_s[jj] - M);
        float L = 0.f;
#pragma unroll
        for (int c = 0; c < 4; ++c)
            L += lbuf[(c * 4 + g) * 16 + r] * __expf(mbuf[(c * 4 + g) * 16 + r] - M);
        Lsum[jj] = L;
    }
#pragma unroll
    for (int c = 0; c < 4; ++c) {
        if (cid == c) {
#pragma unroll
            for (int dblk = 0; dblk < 4; ++dblk)
#pragma unroll
                for (int jj = 0; jj < 4; ++jj) {
                    int off = (g * 16 + lh * 4 + jj) * 64 + dblk * 16 + l15;
                    float v = oacc[dblk][jj] * sc[jj];
                    if (c == 0) Osum[off] = v;
                    else        Osum[off] += v;
                }
        }
        __syncthreads();
    }
    if (cid == 0) {
        __bf16* ob = o + ((size_t)bt * 64 + g * 16) * 512 + h * 64;
#pragma unroll
        for (int dblk = 0; dblk < 4; ++dblk)
#pragma unroll
            for (int jj = 0; jj < 4; ++jj) {
                int r = lh * 4 + jj;
                float v = Osum[(g * 16 + r) * 64 + dblk * 16 + l15] / Lsum[jj];
                ob[(size_t)r * 512 + dblk * 16 + l15] = (__bf16)v;
            }
    }
}

// ---------------------------------------------------------------- launch
extern "C" void kernel_launch(void* const* d_in, const int* in_sizes, int n_in,
                              void* d_out, int out_size, void* d_ws, size_t ws_size,
                              hipStream_t stream) {
    const float* x    = (const float*)d_in[0];
    const float* lat  = (const float*)d_in[1];
    const float* g_m  = (const float*)d_in[2];
    const float* b_m  = (const float*)d_in[3];
    const float* g_l  = (const float*)d_in[4];
    const float* b_l  = (const float*)d_in[5];
    const float* Wq   = (const float*)d_in[6];
    const float* Wkv  = (const float*)d_in[7];
    const float* Wout = (const float*)d_in[8];
    float* out = (float*)d_out;

    char* ws = (char*)d_ws;
    __bf16* concat = (__bf16*)ws; ws += (size_t)34816 * 1024 * 2;
    __bf16* kvb    = (__bf16*)ws; ws += (size_t)34816 * 1024 * 2;
    __bf16* latln  = (__bf16*)ws; ws += (size_t)2048 * 1024 * 2;
    __bf16* qb     = (__bf16*)ws; ws += (size_t)2048 * 512 * 2;
    __bf16* ab     = (__bf16*)ws; ws += (size_t)2048 * 512 * 2;
    __bf16* WqT    = (__bf16*)ws; ws += (size_t)512 * 1024 * 2;
    __bf16* WkvT   = (__bf16*)ws; ws += (size_t)1024 * 1024 * 2;
    __bf16* WoutT  = (__bf16*)ws; ws += (size_t)1024 * 512 * 2;

    // fused: weight transposes (2048 blocks) | LN (34816 blocks)
    prep_kernel<<<2048 + 34816, 256, 0, stream>>>(
        Wq, Wkv, Wout, WqT, WkvT, WoutT,
        x, lat, g_m, b_m, g_l, b_l, concat, latln);

    // kv = concat @ Wkv   (M=34816, N=1024, K=1024); nwg = 272*8 = 2176
    gemm_bf16<true><<<2176, 256, 0, stream>>>(concat, WkvT, kvb, 34816, 1024, 1024, 1.0f, 8);
    // q = latln @ Wq      (M=2048, N=512, K=1024; 0.125 folded in WqT); nwg = 64
    gemm_bf16<true><<<64, 256, 0, stream>>>(latln, WqT, qb, 2048, 512, 1024, 1.0f, 4);

    attn_kernel<<<256, 1024, 0, stream>>>(qb, kvb, ab);

    // out = attn @ Wout   (M=2048, N=1024, K=512); nwg = 16*8 = 128
    gemm_bf16<false><<<128, 256, 0, stream>>>(ab, WoutT, out, 2048, 1024, 512, 1.0f, 8);
}

// Round 11
// 188.650 us; speedup vs baseline: 1.0853x; 1.0853x over previous
//
#include <hip/hip_runtime.h>
#include <hip/hip_bf16.h>
#include <cstdint>

// B=8 T=4 N1=1024 N2=64 DIM=1024 HEADS=8 DHEAD=64 INNER=512
// BT = 32, NR = N1+N2 = 1088, concat rows = 34816
// Pipeline: {weight transpose | LN} fused -> {kv|q} UNIFORM fused GEMM -> attention
//           -> out GEMM
// Fusion via buffer stacking (R10 lesson): A_cat rows [34816,36864) = LN(latents),
// B_cat rows [1024,1536) = WqT, C rows [34816,36864) cols [0,512) = q.
// Block->tile map is scalar-only; kernel body is uniform => no VGPR tax (R9 was 96).

typedef __bf16 bf16x8 __attribute__((ext_vector_type(8)));
typedef __bf16 bf16x4 __attribute__((ext_vector_type(4)));
typedef float  f32x4  __attribute__((ext_vector_type(4)));

__device__ __forceinline__ void gload_lds16(const void* g, void* l) {
    __builtin_amdgcn_global_load_lds(
        (const __attribute__((address_space(1))) unsigned int*)g,
        (__attribute__((address_space(3))) unsigned int*)l, 16, 0, 0);
}

// ---------------------------------------------------------------- prep: transpose + LN
// Blocks [0,2048): weight transpose f32 [K][N] -> bf16 [N][K].
//   [0,512) Wq (x0.125 folded) -> B_cat rows [1024,1536); [512,1536) Wkv -> B_cat rows
//   [0,1024); [1536,2048) Wout -> WoutT.
// Blocks [2048, 2048+34816): LN rows -> A_cat; latent rows also -> A_cat rows 34816+.
__global__ __launch_bounds__(256) void prep_kernel(
    const float* __restrict__ Wq, const float* __restrict__ Wkv,
    const float* __restrict__ Wout,
    __bf16* __restrict__ WqT, __bf16* __restrict__ WkvT, __bf16* __restrict__ WoutT,
    const float* __restrict__ x, const float* __restrict__ lat,
    const float* __restrict__ g_m, const float* __restrict__ b_m,
    const float* __restrict__ g_l, const float* __restrict__ b_l,
    __bf16* __restrict__ concat, __bf16* __restrict__ latln) {
    __shared__ float tile[32][33];
    __shared__ float ss[4], qq[4];
    int id = blockIdx.x;
    if (id < 2048) {
        const float* src; __bf16* dst; int N; int bx, by; float wscale;
        if (id < 512)       { src = Wq;   dst = WqT;   N = 512;
                              bx = id & 15;  by = id >> 4;  wscale = 0.125f; }
        else if (id < 1536) { int i = id - 512;  src = Wkv;  dst = WkvT;  N = 1024;
                              bx = i & 31;  by = i >> 5;  wscale = 1.0f; }
        else                { int i = id - 1536; src = Wout; dst = WoutT; N = 1024;
                              bx = i & 31;  by = i >> 5;  wscale = 1.0f; }
        int K = (id < 1536) ? 1024 : 512;
        int n0 = bx * 32, k0 = by * 32;
        int tx = threadIdx.x & 31, ty = threadIdx.x >> 5;   // 32x8
#pragma unroll
        for (int i = 0; i < 4; ++i)
            tile[ty + i * 8][tx] = src[(size_t)(k0 + ty + i * 8) * N + n0 + tx];
        __syncthreads();
#pragma unroll
        for (int i = 0; i < 4; ++i)
            dst[(size_t)(n0 + ty + i * 8) * K + k0 + tx] =
                (__bf16)(tile[tx][ty + i * 8] * wscale);
        return;
    }
    // ---------- layernorm ----------
    int row = id - 2048;                // 0..34815
    int bt  = row / 1088;
    int r   = row - bt * 1088;
    const float *src, *g, *b;
    if (r < 1024) { src = x   + ((size_t)(bt * 1024 + r) << 10);        g = g_m; b = b_m; }
    else          { src = lat + ((size_t)(bt * 64 + (r - 1024)) << 10); g = g_l; b = b_l; }
    int t = threadIdx.x;
    float4 v = ((const float4*)src)[t];
    float s = v.x + v.y + v.z + v.w;
    float q = v.x * v.x + v.y * v.y + v.z * v.z + v.w * v.w;
#pragma unroll
    for (int m = 1; m < 64; m <<= 1) { s += __shfl_xor(s, m); q += __shfl_xor(q, m); }
    int w = t >> 6;
    if ((t & 63) == 0) { ss[w] = s; qq[w] = q; }
    __syncthreads();
    s = ss[0] + ss[1] + ss[2] + ss[3];
    q = qq[0] + qq[1] + qq[2] + qq[3];
    float mean = s * (1.0f / 1024.0f);
    float var  = q * (1.0f / 1024.0f) - mean * mean;
    float rstd = rsqrtf(var + 1e-5f);
    float4 gv = ((const float4*)g)[t];
    float4 bv = ((const float4*)b)[t];
    bf16x4 o;
    o[0] = (__bf16)((v.x - mean) * rstd * gv.x + bv.x);
    o[1] = (__bf16)((v.y - mean) * rstd * gv.y + bv.y);
    o[2] = (__bf16)((v.z - mean) * rstd * gv.z + bv.z);
    o[3] = (__bf16)((v.w - mean) * rstd * gv.w + bv.w);
    *(bf16x4*)(concat + ((size_t)row << 10) + t * 4) = o;
    if (r >= 1024)
        *(bf16x4*)(latln + ((size_t)(bt * 64 + (r - 1024)) << 10) + t * 4) = o;
}

// ---------------------------------------------------------------- uniform fused {kv|q}
// C[.][1024] = A_cat[.][1024] @ B_cat[.][1024]^T rows. 128x128 tile, BK=64, 4 waves.
// Blocks [0,2176): kv tiles (bm<272, bn<8). Blocks [2176,2240): q tiles
// (bm=272..287, bn=8..11; C col = (bn&7)*128 -> [0,512)). Body is block-uniform.
#define BKK 64

__global__ __launch_bounds__(256) void qkv_gemm(
    const __bf16* __restrict__ A, const __bf16* __restrict__ Bt,
    __bf16* __restrict__ C) {
    __shared__ __bf16 As[128 * BKK];
    __shared__ __bf16 Bs[128 * BKK];
    constexpr int K = 1024, N = 1024;
    int tid  = threadIdx.x;
    int lane = tid & 63, wave = tid >> 6;
    int id = blockIdx.x;

    int bm, bn;                      // scalar-only divergence
    if (id < 2176) {
        int swz = (id & 7) * 272 + (id >> 3);
        bm = swz >> 3; bn = swz & 7;
    } else {
        int i2 = id - 2176;
        int swz = (i2 & 7) * 8 + (i2 >> 3);
        bm = 272 + (swz >> 2); bn = 8 + (swz & 3);
    }

    int wr = (wave >> 1) * 64, wc = (wave & 1) * 64;
    int l15 = lane & 15, lh = lane >> 4;
    int srow = lane >> 3;
    int scol = ((lane & 7) ^ srow) * 8;           // inverse-swizzled source column

    const __bf16* abase[4];
    const __bf16* bbase[4];
#pragma unroll
    for (int i = 0; i < 4; ++i) {
        int r = wave * 32 + i * 8 + srow;
        abase[i] = A  + (size_t)(bm * 128 + r) * K + scol;
        bbase[i] = Bt + (size_t)(bn * 128 + r) * K + scol;
    }

    f32x4 acc[4][4] = {};

    for (int k0 = 0; k0 < K; k0 += BKK) {
        __syncthreads();
#pragma unroll
        for (int i = 0; i < 4; ++i) {
            gload_lds16(abase[i] + k0, &As[(wave * 32 + i * 8) * BKK]);
            gload_lds16(bbase[i] + k0, &Bs[(wave * 32 + i * 8) * BKK]);
        }
        __syncthreads();
#pragma unroll
        for (int kk = 0; kk < BKK; kk += 32) {
            int cb = (kk + lh * 8) * 2;
            bf16x8 af[4], bfr[4];
#pragma unroll
            for (int mi = 0; mi < 4; ++mi) {
                int r = wr + mi * 16 + l15;
                af[mi] = *(const bf16x8*)((const char*)As + r * 128 + (cb ^ ((r & 7) << 4)));
            }
#pragma unroll
            for (int ni = 0; ni < 4; ++ni) {
                int r = wc + ni * 16 + l15;
                bfr[ni] = *(const bf16x8*)((const char*)Bs + r * 128 + (cb ^ ((r & 7) << 4)));
            }
#pragma unroll
            for (int mi = 0; mi < 4; ++mi)
#pragma unroll
                for (int ni = 0; ni < 4; ++ni)
                    acc[mi][ni] = __builtin_amdgcn_mfma_f32_16x16x32_bf16(
                        af[mi], bfr[ni], acc[mi][ni], 0, 0, 0);
        }
    }
    // epilogue: D row = lh*4+jj, col = l15 (m89-verified). q cols fold via bn&7.
#pragma unroll
    for (int mi = 0; mi < 4; ++mi)
#pragma unroll
        for (int ni = 0; ni < 4; ++ni)
#pragma unroll
            for (int jj = 0; jj < 4; ++jj) {
                int row = bm * 128 + wr + mi * 16 + lh * 4 + jj;
                int col = (bn & 7) * 128 + wc + ni * 16 + l15;
                C[(size_t)row * N + col] = (__bf16)acc[mi][ni][jj];
            }
}

// ---------------------------------------------------------------- GEMM 128^2 (m97-style)
template <bool OUT_BF16>
__global__ __launch_bounds__(256) void gemm_bf16(
    const __bf16* __restrict__ A, const __bf16* __restrict__ Bt,
    void* __restrict__ C, int M, int N, int K, float scale, int gx) {
    __shared__ __bf16 As[128 * BKK];
    __shared__ __bf16 Bs[128 * BKK];
    int tid  = threadIdx.x;
    int lane = tid & 63, wave = tid >> 6;

    int nwg = gridDim.x;
    int id  = blockIdx.x;
    int cpx = nwg >> 3;
    int swz = (id & 7) * cpx + (id >> 3);
    int bm = swz / gx, bn = swz % gx;

    int wr = (wave >> 1) * 64, wc = (wave & 1) * 64;
    int l15 = lane & 15, lh = lane >> 4;
    int srow = lane >> 3;
    int scol = ((lane & 7) ^ srow) * 8;           // inverse-swizzled source column

    const __bf16* abase[4];
    const __bf16* bbase[4];
#pragma unroll
    for (int i = 0; i < 4; ++i) {
        int r = wave * 32 + i * 8 + srow;
        abase[i] = A + (size_t)(bm * 128 + r) * K + scol;
        bbase[i] = Bt + (size_t)(bn * 128 + r) * K + scol;
    }

    f32x4 acc[4][4] = {};

    for (int k0 = 0; k0 < K; k0 += BKK) {
        __syncthreads();
#pragma unroll
        for (int i = 0; i < 4; ++i) {
            gload_lds16(abase[i] + k0, &As[(wave * 32 + i * 8) * BKK]);
            gload_lds16(bbase[i] + k0, &Bs[(wave * 32 + i * 8) * BKK]);
        }
        __syncthreads();
#pragma unroll
        for (int kk = 0; kk < BKK; kk += 32) {
            int cb = (kk + lh * 8) * 2;
            bf16x8 af[4], bfr[4];
#pragma unroll
            for (int mi = 0; mi < 4; ++mi) {
                int r = wr + mi * 16 + l15;
                af[mi] = *(const bf16x8*)((const char*)As + r * 128 + (cb ^ ((r & 7) << 4)));
            }
#pragma unroll
            for (int ni = 0; ni < 4; ++ni) {
                int r = wc + ni * 16 + l15;
                bfr[ni] = *(const bf16x8*)((const char*)Bs + r * 128 + (cb ^ ((r & 7) << 4)));
            }
#pragma unroll
            for (int mi = 0; mi < 4; ++mi)
#pragma unroll
                for (int ni = 0; ni < 4; ++ni)
                    acc[mi][ni] = __builtin_amdgcn_mfma_f32_16x16x32_bf16(
                        af[mi], bfr[ni], acc[mi][ni], 0, 0, 0);
        }
    }
#pragma unroll
    for (int mi = 0; mi < 4; ++mi)
#pragma unroll
        for (int ni = 0; ni < 4; ++ni)
#pragma unroll
            for (int jj = 0; jj < 4; ++jj) {
                int row = bm * 128 + wr + mi * 16 + lh * 4 + jj;
                int col = bn * 128 + wc + ni * 16 + l15;
                float val = acc[mi][ni][jj] * scale;
                if (OUT_BF16) ((__bf16*)C)[(size_t)row * N + col] = (__bf16)val;
                else          ((float*)C)[(size_t)row * N + col]  = val;
            }
}

// ---------------------------------------------------------------- attention
__global__ __launch_bounds__(1024) void attn_kernel(
    const __bf16* __restrict__ q,    // [32][64] rows x 1024-stride, cols [0,512) used
    const __bf16* __restrict__ kv,   // [32][1088][1024]  (k: cols 0..511, v: 512..1023)
    __bf16* __restrict__ o) {        // [32][64][512]
    int blk = blockIdx.x;            // 0..255
    int bt = blk >> 3, h = blk & 7;
    int tid = threadIdx.x;
    int cid  = tid >> 8;             // KV chunk 0..3
    int ctid = tid & 255;
    int wave = tid >> 6;             // 0..15
    int g    = wave & 3;             // q-row group
    int lane = tid & 63, l15 = lane & 15, lh = lane >> 4;

    __shared__ __bf16 vT[4][64 * 64];     // per-chunk [d][j] swizzled, 32 KB
    __shared__ __bf16 Pl[16][16 * 64];    // per-wave  [r][j] swizzled, 32 KB
    float* mbuf = (float*)&vT[1][0];      // [4][4][16]  (aliased, dead region)
    float* lbuf = mbuf + 256;             // [4][4][16]
    float* Osum = (float*)&Pl[0][0];      // [4][16][64]

    const __bf16* qbase = q + ((size_t)bt * 64 + g * 16) * 1024 + h * 64;
    bf16x8 qf[2];
    qf[0] = *(const bf16x8*)(qbase + (size_t)l15 * 1024 + lh * 8);
    qf[1] = *(const bf16x8*)(qbase + (size_t)l15 * 1024 + 32 + lh * 8);

    const __bf16* kvbt = kv + (size_t)bt * 1088 * 1024;

    float m_s[4], l_s[4];
    f32x4 oacc[4];
#pragma unroll
    for (int jj = 0; jj < 4; ++jj) { m_s[jj] = -1e30f; l_s[jj] = 0.f; }
#pragma unroll
    for (int d = 0; d < 4; ++d) oacc[d] = f32x4{0.f, 0.f, 0.f, 0.f};

    for (int it = 0; it < 5; ++it) {
        int tile = it * 4 + cid;
        bool act = tile < 17;
        int j0 = tile * 64;
        __syncthreads();
        if (act) {
#pragma unroll
            for (int it2 = 0; it2 < 2; ++it2) {
                int idx = it2 * 256 + ctid;
                int j = idx >> 3, c = idx & 7;
                bf16x8 vv = *(const bf16x8*)(kvbt + (size_t)(j0 + j) * 1024 + 512 + h * 64 + c * 8);
#pragma unroll
                for (int e = 0; e < 8; ++e) {
                    int d = c * 8 + e;
                    *(__bf16*)((char*)vT[cid] + d * 128 + ((j * 2) ^ ((d & 7) << 4))) = vv[e];
                }
            }
        }
        __syncthreads();
        if (act) {
            f32x4 s[4];
            f32x4 zero = {0.f, 0.f, 0.f, 0.f};
#pragma unroll
            for (int ni = 0; ni < 4; ++ni) {
                const __bf16* kp = kvbt + (size_t)(j0 + ni * 16 + l15) * 1024 + h * 64;
                bf16x8 kf0 = *(const bf16x8*)(kp + lh * 8);
                bf16x8 kf1 = *(const bf16x8*)(kp + 32 + lh * 8);
                f32x4 t0 = __builtin_amdgcn_mfma_f32_16x16x32_bf16(qf[0], kf0, zero, 0, 0, 0);
                s[ni]    = __builtin_amdgcn_mfma_f32_16x16x32_bf16(qf[1], kf1, t0,   0, 0, 0);
            }
            float tm[4];
#pragma unroll
            for (int jj = 0; jj < 4; ++jj)
                tm[jj] = fmaxf(fmaxf(s[0][jj], s[1][jj]), fmaxf(s[2][jj], s[3][jj]));
#pragma unroll
            for (int m = 1; m < 16; m <<= 1)
#pragma unroll
                for (int jj = 0; jj < 4; ++jj) tm[jj] = fmaxf(tm[jj], __shfl_xor(tm[jj], m));
            float alpha[4];
#pragma unroll
            for (int jj = 0; jj < 4; ++jj) {
                float mn = fmaxf(m_s[jj], tm[jj]);
                alpha[jj] = __expf(m_s[jj] - mn);
                m_s[jj] = mn;
            }
            float p[4][4];
            float ts[4] = {0.f, 0.f, 0.f, 0.f};
#pragma unroll
            for (int ni = 0; ni < 4; ++ni)
#pragma unroll
                for (int jj = 0; jj < 4; ++jj) {
                    p[ni][jj] = __expf(s[ni][jj] - m_s[jj]);
                    ts[jj] += p[ni][jj];
                }
#pragma unroll
            for (int m = 1; m < 16; m <<= 1)
#pragma unroll
                for (int jj = 0; jj < 4; ++jj) ts[jj] += __shfl_xor(ts[jj], m);
#pragma unroll
            for (int jj = 0; jj < 4; ++jj) l_s[jj] = l_s[jj] * alpha[jj] + ts[jj];
#pragma unroll
            for (int d = 0; d < 4; ++d)
#pragma unroll
                for (int jj = 0; jj < 4; ++jj) oacc[d][jj] *= alpha[jj];
#pragma unroll
            for (int ni = 0; ni < 4; ++ni)
#pragma unroll
                for (int jj = 0; jj < 4; ++jj) {
                    int r = lh * 4 + jj, j = ni * 16 + l15;
                    *(__bf16*)((char*)Pl[wave] + r * 128 + ((j * 2) ^ ((r & 7) << 4))) =
                        (__bf16)p[ni][jj];
                }
        }
        __syncthreads();   // P write -> P read
        if (act) {
            bf16x8 pf[2];
            pf[0] = *(const bf16x8*)((char*)Pl[wave] + l15 * 128 + ((lh * 16)      ^ ((l15 & 7) << 4)));
            pf[1] = *(const bf16x8*)((char*)Pl[wave] + l15 * 128 + ((64 + lh * 16) ^ ((l15 & 7) << 4)));
#pragma unroll
            for (int dblk = 0; dblk < 4; ++dblk) {
                int dr = dblk * 16 + l15;
                bf16x8 vf0 = *(const bf16x8*)((char*)vT[cid] + dr * 128 + ((lh * 16)      ^ ((dr & 7) << 4)));
                bf16x8 vf1 = *(const bf16x8*)((char*)vT[cid] + dr * 128 + ((64 + lh * 16) ^ ((dr & 7) << 4)));
                oacc[dblk] = __builtin_amdgcn_mfma_f32_16x16x32_bf16(pf[0], vf0, oacc[dblk], 0, 0, 0);
                oacc[dblk] = __builtin_amdgcn_mfma_f32_16x16x32_bf16(pf[1], vf1, oacc[dblk], 0, 0, 0);
            }
        }
    }

    // -------- flash merge of 4 chunk-partials --------
    __syncthreads();
    if (l15 == 0) {
#pragma unroll
        for (int jj = 0; jj < 4; ++jj) {
            mbuf[(cid * 4 + g) * 16 + lh * 4 + jj] = m_s[jj];
            lbuf[(cid * 4 + g) * 16 + lh * 4 + jj] = l_s[jj];
        }
    }
    __syncthreads();
    float sc[4], Lsum[4];
#pragma unroll
    for (int jj = 0; jj < 4; ++jj) {
        int r = lh * 4 + jj;
        float M = mbuf[(0 * 4 + g) * 16 + r];
#pragma unroll
        for (int c = 1; c < 4; ++c) M = fmaxf(M, mbuf[(c * 4 + g) * 16 + r]);
        sc[jj] = __expf(m_s[jj] - M);
        float L = 0.f;
#pragma unroll
        for (int c = 0; c < 4; ++c)
            L += lbuf[(c * 4 + g) * 16 + r] * __expf(mbuf[(c * 4 + g) * 16 + r] - M);
        Lsum[jj] = L;
    }
#pragma unroll
    for (int c = 0; c < 4; ++c) {
        if (cid == c) {
#pragma unroll
            for (int dblk = 0; dblk < 4; ++dblk)
#pragma unroll
                for (int jj = 0; jj < 4; ++jj) {
                    int off = (g * 16 + lh * 4 + jj) * 64 + dblk * 16 + l15;
                    float v = oacc[dblk][jj] * sc[jj];
                    if (c == 0) Osum[off] = v;
                    else        Osum[off] += v;
                }
        }
        __syncthreads();
    }
    if (cid == 0) {
        __bf16* ob = o + ((size_t)bt * 64 + g * 16) * 512 + h * 64;
#pragma unroll
        for (int dblk = 0; dblk < 4; ++dblk)
#pragma unroll
            for (int jj = 0; jj < 4; ++jj) {
                int r = lh * 4 + jj;
                float v = Osum[(g * 16 + r) * 64 + dblk * 16 + l15] / Lsum[jj];
                ob[(size_t)r * 512 + dblk * 16 + l15] = (__bf16)v;
            }
    }
}

// ---------------------------------------------------------------- launch
extern "C" void kernel_launch(void* const* d_in, const int* in_sizes, int n_in,
                              void* d_out, int out_size, void* d_ws, size_t ws_size,
                              hipStream_t stream) {
    const float* x    = (const float*)d_in[0];
    const float* lat  = (const float*)d_in[1];
    const float* g_m  = (const float*)d_in[2];
    const float* b_m  = (const float*)d_in[3];
    const float* g_l  = (const float*)d_in[4];
    const float* b_l  = (const float*)d_in[5];
    const float* Wq   = (const float*)d_in[6];
    const float* Wkv  = (const float*)d_in[7];
    const float* Wout = (const float*)d_in[8];
    float* out = (float*)d_out;

    char* ws = (char*)d_ws;
    __bf16* A_cat = (__bf16*)ws; ws += (size_t)36864 * 1024 * 2;   // LN(concat) + latln
    __bf16* kvq   = (__bf16*)ws; ws += (size_t)36864 * 1024 * 2;   // kv + q
    __bf16* ab    = (__bf16*)ws; ws += (size_t)2048 * 512 * 2;
    __bf16* B_cat = (__bf16*)ws; ws += (size_t)1536 * 1024 * 2;    // WkvT + WqT
    __bf16* WoutT = (__bf16*)ws; ws += (size_t)1024 * 512 * 2;

    __bf16* latln = A_cat + (size_t)34816 * 1024;
    __bf16* WkvT  = B_cat;
    __bf16* WqT   = B_cat + (size_t)1024 * 1024;
    __bf16* qb    = kvq   + (size_t)34816 * 1024;   // rows 34816+, cols [0,512)

    // fused: weight transposes (2048 blocks) | LN (34816 blocks)
    prep_kernel<<<2048 + 34816, 256, 0, stream>>>(
        Wq, Wkv, Wout, WqT, WkvT, WoutT,
        x, lat, g_m, b_m, g_l, b_l, A_cat, latln);

    // uniform fused: kv (2176 blocks) | q (64 blocks, overlapped in tail)
    qkv_gemm<<<2240, 256, 0, stream>>>(A_cat, B_cat, kvq);

    attn_kernel<<<256, 1024, 0, stream>>>(qb, kvq, ab);

    // out = attn @ Wout   (M=2048, N=1024, K=512); nwg = 16*8 = 128
    gemm_bf16<false><<<128, 256, 0, stream>>>(ab, WoutT, out, 2048, 1024, 512, 1.0f, 8);
}

// Round 12
// 186.690 us; speedup vs baseline: 1.0967x; 1.0105x over previous
//
#include <hip/hip_runtime.h>
#include <hip/hip_bf16.h>
#include <cstdint>

// B=8 T=4 N1=1024 N2=64 DIM=1024 HEADS=8 DHEAD=64 INNER=512
// BT = 32, NR = N1+N2 = 1088, concat rows = 34816
// Pipeline: {weight transpose | LN} fused -> {kv|q} uniform fused GEMM -> attention
//           -> out GEMM
// R11 lesson: constexpr K fully unrolls the K-loop -> +16 VGPR -> -9% occupancy.
// K is a RUNTIME arg here (R10's 80-VGPR body), fusion via buffer stacking kept.

typedef __bf16 bf16x8 __attribute__((ext_vector_type(8)));
typedef __bf16 bf16x4 __attribute__((ext_vector_type(4)));
typedef float  f32x4  __attribute__((ext_vector_type(4)));

__device__ __forceinline__ void gload_lds16(const void* g, void* l) {
    __builtin_amdgcn_global_load_lds(
        (const __attribute__((address_space(1))) unsigned int*)g,
        (__attribute__((address_space(3))) unsigned int*)l, 16, 0, 0);
}

// ---------------------------------------------------------------- prep: transpose + LN
// Blocks [0,2048): weight transpose f32 [K][N] -> bf16 [N][K].
//   [0,512) Wq (x0.125) -> B_cat rows [1024,1536); [512,1536) Wkv -> B_cat rows [0,1024);
//   [1536,2048) Wout -> WoutT.
// Blocks [2048, 2048+34816): LN rows -> A_cat; latent rows also -> A_cat rows 34816+.
__global__ __launch_bounds__(256) void prep_kernel(
    const float* __restrict__ Wq, const float* __restrict__ Wkv,
    const float* __restrict__ Wout,
    __bf16* __restrict__ WqT, __bf16* __restrict__ WkvT, __bf16* __restrict__ WoutT,
    const float* __restrict__ x, const float* __restrict__ lat,
    const float* __restrict__ g_m, const float* __restrict__ b_m,
    const float* __restrict__ g_l, const float* __restrict__ b_l,
    __bf16* __restrict__ concat, __bf16* __restrict__ latln) {
    __shared__ float tile[32][33];
    __shared__ float ss[4], qq[4];
    int id = blockIdx.x;
    if (id < 2048) {
        const float* src; __bf16* dst; int N; int bx, by; float wscale;
        if (id < 512)       { src = Wq;   dst = WqT;   N = 512;
                              bx = id & 15;  by = id >> 4;  wscale = 0.125f; }
        else if (id < 1536) { int i = id - 512;  src = Wkv;  dst = WkvT;  N = 1024;
                              bx = i & 31;  by = i >> 5;  wscale = 1.0f; }
        else                { int i = id - 1536; src = Wout; dst = WoutT; N = 1024;
                              bx = i & 31;  by = i >> 5;  wscale = 1.0f; }
        int K = (id < 1536) ? 1024 : 512;
        int n0 = bx * 32, k0 = by * 32;
        int tx = threadIdx.x & 31, ty = threadIdx.x >> 5;   // 32x8
#pragma unroll
        for (int i = 0; i < 4; ++i)
            tile[ty + i * 8][tx] = src[(size_t)(k0 + ty + i * 8) * N + n0 + tx];
        __syncthreads();
#pragma unroll
        for (int i = 0; i < 4; ++i)
            dst[(size_t)(n0 + ty + i * 8) * K + k0 + tx] =
                (__bf16)(tile[tx][ty + i * 8] * wscale);
        return;
    }
    // ---------- layernorm ----------
    int row = id - 2048;                // 0..34815
    int bt  = row / 1088;
    int r   = row - bt * 1088;
    const float *src, *g, *b;
    if (r < 1024) { src = x   + ((size_t)(bt * 1024 + r) << 10);        g = g_m; b = b_m; }
    else          { src = lat + ((size_t)(bt * 64 + (r - 1024)) << 10); g = g_l; b = b_l; }
    int t = threadIdx.x;
    float4 v = ((const float4*)src)[t];
    float s = v.x + v.y + v.z + v.w;
    float q = v.x * v.x + v.y * v.y + v.z * v.z + v.w * v.w;
#pragma unroll
    for (int m = 1; m < 64; m <<= 1) { s += __shfl_xor(s, m); q += __shfl_xor(q, m); }
    int w = t >> 6;
    if ((t & 63) == 0) { ss[w] = s; qq[w] = q; }
    __syncthreads();
    s = ss[0] + ss[1] + ss[2] + ss[3];
    q = qq[0] + qq[1] + qq[2] + qq[3];
    float mean = s * (1.0f / 1024.0f);
    float var  = q * (1.0f / 1024.0f) - mean * mean;
    float rstd = rsqrtf(var + 1e-5f);
    float4 gv = ((const float4*)g)[t];
    float4 bv = ((const float4*)b)[t];
    bf16x4 o;
    o[0] = (__bf16)((v.x - mean) * rstd * gv.x + bv.x);
    o[1] = (__bf16)((v.y - mean) * rstd * gv.y + bv.y);
    o[2] = (__bf16)((v.z - mean) * rstd * gv.z + bv.z);
    o[3] = (__bf16)((v.w - mean) * rstd * gv.w + bv.w);
    *(bf16x4*)(concat + ((size_t)row << 10) + t * 4) = o;
    if (r >= 1024)
        *(bf16x4*)(latln + ((size_t)(bt * 64 + (r - 1024)) << 10) + t * 4) = o;
}

// ---------------------------------------------------------------- uniform fused {kv|q}
// C[.][1024] = A_cat rows @ B_cat rows^T. 128x128 tile, BK=64, 4 waves, runtime K.
// Blocks [0,2176): kv tiles (bm<272, bn<8). Blocks [2176,2240): q tiles
// (bm=272..287, bn=8..11; C col = (bn&7)*128 -> [0,512)). Body is block-uniform.
#define BKK 64

__global__ __launch_bounds__(256) void qkv_gemm(
    const __bf16* __restrict__ A, const __bf16* __restrict__ Bt,
    __bf16* __restrict__ C, int K) {
    __shared__ __bf16 As[128 * BKK];
    __shared__ __bf16 Bs[128 * BKK];
    int tid  = threadIdx.x;
    int lane = tid & 63, wave = tid >> 6;
    int id = blockIdx.x;

    int bm, bn;                      // scalar-only divergence
    if (id < 2176) {
        int swz = (id & 7) * 272 + (id >> 3);
        bm = swz >> 3; bn = swz & 7;
    } else {
        int i2 = id - 2176;
        int swz = (i2 & 7) * 8 + (i2 >> 3);
        bm = 272 + (swz >> 2); bn = 8 + (swz & 3);
    }

    int wr = (wave >> 1) * 64, wc = (wave & 1) * 64;
    int l15 = lane & 15, lh = lane >> 4;
    int srow = lane >> 3;
    int scol = ((lane & 7) ^ srow) * 8;           // inverse-swizzled source column

    const __bf16* abase[4];
    const __bf16* bbase[4];
#pragma unroll
    for (int i = 0; i < 4; ++i) {
        int r = wave * 32 + i * 8 + srow;
        abase[i] = A  + (size_t)(bm * 128 + r) * K + scol;
        bbase[i] = Bt + (size_t)(bn * 128 + r) * K + scol;
    }

    f32x4 acc[4][4] = {};

#pragma unroll 1
    for (int k0 = 0; k0 < K; k0 += BKK) {
        __syncthreads();
#pragma unroll
        for (int i = 0; i < 4; ++i) {
            gload_lds16(abase[i] + k0, &As[(wave * 32 + i * 8) * BKK]);
            gload_lds16(bbase[i] + k0, &Bs[(wave * 32 + i * 8) * BKK]);
        }
        __syncthreads();
#pragma unroll
        for (int kk = 0; kk < BKK; kk += 32) {
            int cb = (kk + lh * 8) * 2;
            bf16x8 af[4], bfr[4];
#pragma unroll
            for (int mi = 0; mi < 4; ++mi) {
                int r = wr + mi * 16 + l15;
                af[mi] = *(const bf16x8*)((const char*)As + r * 128 + (cb ^ ((r & 7) << 4)));
            }
#pragma unroll
            for (int ni = 0; ni < 4; ++ni) {
                int r = wc + ni * 16 + l15;
                bfr[ni] = *(const bf16x8*)((const char*)Bs + r * 128 + (cb ^ ((r & 7) << 4)));
            }
#pragma unroll
            for (int mi = 0; mi < 4; ++mi)
#pragma unroll
                for (int ni = 0; ni < 4; ++ni)
                    acc[mi][ni] = __builtin_amdgcn_mfma_f32_16x16x32_bf16(
                        af[mi], bfr[ni], acc[mi][ni], 0, 0, 0);
        }
    }
    // epilogue: D row = lh*4+jj, col = l15 (m89-verified). q cols fold via bn&7.
#pragma unroll
    for (int mi = 0; mi < 4; ++mi)
#pragma unroll
        for (int ni = 0; ni < 4; ++ni)
#pragma unroll
            for (int jj = 0; jj < 4; ++jj) {
                int row = bm * 128 + wr + mi * 16 + lh * 4 + jj;
                int col = (bn & 7) * 128 + wc + ni * 16 + l15;
                C[(size_t)row * 1024 + col] = (__bf16)acc[mi][ni][jj];
            }
}

// ---------------------------------------------------------------- GEMM 128^2 (m97-style)
template <bool OUT_BF16>
__global__ __launch_bounds__(256) void gemm_bf16(
    const __bf16* __restrict__ A, const __bf16* __restrict__ Bt,
    void* __restrict__ C, int M, int N, int K, float scale, int gx) {
    __shared__ __bf16 As[128 * BKK];
    __shared__ __bf16 Bs[128 * BKK];
    int tid  = threadIdx.x;
    int lane = tid & 63, wave = tid >> 6;

    int nwg = gridDim.x;
    int id  = blockIdx.x;
    int cpx = nwg >> 3;
    int swz = (id & 7) * cpx + (id >> 3);
    int bm = swz / gx, bn = swz % gx;

    int wr = (wave >> 1) * 64, wc = (wave & 1) * 64;
    int l15 = lane & 15, lh = lane >> 4;
    int srow = lane >> 3;
    int scol = ((lane & 7) ^ srow) * 8;           // inverse-swizzled source column

    const __bf16* abase[4];
    const __bf16* bbase[4];
#pragma unroll
    for (int i = 0; i < 4; ++i) {
        int r = wave * 32 + i * 8 + srow;
        abase[i] = A + (size_t)(bm * 128 + r) * K + scol;
        bbase[i] = Bt + (size_t)(bn * 128 + r) * K + scol;
    }

    f32x4 acc[4][4] = {};

#pragma unroll 1
    for (int k0 = 0; k0 < K; k0 += BKK) {
        __syncthreads();
#pragma unroll
        for (int i = 0; i < 4; ++i) {
            gload_lds16(abase[i] + k0, &As[(wave * 32 + i * 8) * BKK]);
            gload_lds16(bbase[i] + k0, &Bs[(wave * 32 + i * 8) * BKK]);
        }
        __syncthreads();
#pragma unroll
        for (int kk = 0; kk < BKK; kk += 32) {
            int cb = (kk + lh * 8) * 2;
            bf16x8 af[4], bfr[4];
#pragma unroll
            for (int mi = 0; mi < 4; ++mi) {
                int r = wr + mi * 16 + l15;
                af[mi] = *(const bf16x8*)((const char*)As + r * 128 + (cb ^ ((r & 7) << 4)));
            }
#pragma unroll
            for (int ni = 0; ni < 4; ++ni) {
                int r = wc + ni * 16 + l15;
                bfr[ni] = *(const bf16x8*)((const char*)Bs + r * 128 + (cb ^ ((r & 7) << 4)));
            }
#pragma unroll
            for (int mi = 0; mi < 4; ++mi)
#pragma unroll
                for (int ni = 0; ni < 4; ++ni)
                    acc[mi][ni] = __builtin_amdgcn_mfma_f32_16x16x32_bf16(
                        af[mi], bfr[ni], acc[mi][ni], 0, 0, 0);
        }
    }
#pragma unroll
    for (int mi = 0; mi < 4; ++mi)
#pragma unroll
        for (int ni = 0; ni < 4; ++ni)
#pragma unroll
            for (int jj = 0; jj < 4; ++jj) {
                int row = bm * 128 + wr + mi * 16 + lh * 4 + jj;
                int col = bn * 128 + wc + ni * 16 + l15;
                float val = acc[mi][ni][jj] * scale;
                if (OUT_BF16) ((__bf16*)C)[(size_t)row * N + col] = (__bf16)val;
                else          ((float*)C)[(size_t)row * N + col]  = val;
            }
}

// ---------------------------------------------------------------- attention
__global__ __launch_bounds__(1024) void attn_kernel(
    const __bf16* __restrict__ q,    // [32][64] rows x 1024-stride, cols [0,512) used
    const __bf16* __restrict__ kv,   // [32][1088][1024]  (k: cols 0..511, v: 512..1023)
    __bf16* __restrict__ o) {        // [32][64][512]
    int blk = blockIdx.x;            // 0..255
    int bt = blk >> 3, h = blk & 7;
    int tid = threadIdx.x;
    int cid  = tid >> 8;             // KV chunk 0..3
    int ctid = tid & 255;
    int wave = tid >> 6;             // 0..15
    int g    = wave & 3;             // q-row group
    int lane = tid & 63, l15 = lane & 15, lh = lane >> 4;

    __shared__ __bf16 vT[4][64 * 64];     // per-chunk [d][j] swizzled, 32 KB
    __shared__ __bf16 Pl[16][16 * 64];    // per-wave  [r][j] swizzled, 32 KB
    float* mbuf = (float*)&vT[1][0];      // [4][4][16]  (aliased, dead region)
    float* lbuf = mbuf + 256;             // [4][4][16]
    float* Osum = (float*)&Pl[0][0];      // [4][16][64]

    const __bf16* qbase = q + ((size_t)bt * 64 + g * 16) * 1024 + h * 64;
    bf16x8 qf[2];
    qf[0] = *(const bf16x8*)(qbase + (size_t)l15 * 1024 + lh * 8);
    qf[1] = *(const bf16x8*)(qbase + (size_t)l15 * 1024 + 32 + lh * 8);

    const __bf16* kvbt = kv + (size_t)bt * 1088 * 1024;

    float m_s[4], l_s[4];
    f32x4 oacc[4];
#pragma unroll
    for (int jj = 0; jj < 4; ++jj) { m_s[jj] = -1e30f; l_s[jj] = 0.f; }
#pragma unroll
    for (int d = 0; d < 4; ++d) oacc[d] = f32x4{0.f, 0.f, 0.f, 0.f};

    for (int it = 0; it < 5; ++it) {
        int tile = it * 4 + cid;
        bool act = tile < 17;
        int j0 = tile * 64;
        __syncthreads();
        if (act) {
#pragma unroll
            for (int it2 = 0; it2 < 2; ++it2) {
                int idx = it2 * 256 + ctid;
                int j = idx >> 3, c = idx & 7;
                bf16x8 vv = *(const bf16x8*)(kvbt + (size_t)(j0 + j) * 1024 + 512 + h * 64 + c * 8);
#pragma unroll
                for (int e = 0; e < 8; ++e) {
                    int d = c * 8 + e;
                    *(__bf16*)((char*)vT[cid] + d * 128 + ((j * 2) ^ ((d & 7) << 4))) = vv[e];
                }
            }
        }
        __syncthreads();
        if (act) {
            f32x4 s[4];
            f32x4 zero = {0.f, 0.f, 0.f, 0.f};
#pragma unroll
            for (int ni = 0; ni < 4; ++ni) {
                const __bf16* kp = kvbt + (size_t)(j0 + ni * 16 + l15) * 1024 + h * 64;
                bf16x8 kf0 = *(const bf16x8*)(kp + lh * 8);
                bf16x8 kf1 = *(const bf16x8*)(kp + 32 + lh * 8);
                f32x4 t0 = __builtin_amdgcn_mfma_f32_16x16x32_bf16(qf[0], kf0, zero, 0, 0, 0);
                s[ni]    = __builtin_amdgcn_mfma_f32_16x16x32_bf16(qf[1], kf1, t0,   0, 0, 0);
            }
            float tm[4];
#pragma unroll
            for (int jj = 0; jj < 4; ++jj)
                tm[jj] = fmaxf(fmaxf(s[0][jj], s[1][jj]), fmaxf(s[2][jj], s[3][jj]));
#pragma unroll
            for (int m = 1; m < 16; m <<= 1)
#pragma unroll
                for (int jj = 0; jj < 4; ++jj) tm[jj] = fmaxf(tm[jj], __shfl_xor(tm[jj], m));
            float alpha[4];
#pragma unroll
            for (int jj = 0; jj < 4; ++jj) {
                float mn = fmaxf(m_s[jj], tm[jj]);
                alpha[jj] = __expf(m_s[jj] - mn);
                m_s[jj] = mn;
            }
            float p[4][4];
            float ts[4] = {0.f, 0.f, 0.f, 0.f};
#pragma unroll
            for (int ni = 0; ni < 4; ++ni)
#pragma unroll
                for (int jj = 0; jj < 4; ++jj) {
                    p[ni][jj] = __expf(s[ni][jj] - m_s[jj]);
                    ts[jj] += p[ni][jj];
                }
#pragma unroll
            for (int m = 1; m < 16; m <<= 1)
#pragma unroll
                for (int jj = 0; jj < 4; ++jj) ts[jj] += __shfl_xor(ts[jj], m);
#pragma unroll
            for (int jj = 0; jj < 4; ++jj) l_s[jj] = l_s[jj] * alpha[jj] + ts[jj];
#pragma unroll
            for (int d = 0; d < 4; ++d)
#pragma unroll
                for (int jj = 0; jj < 4; ++jj) oacc[d][jj] *= alpha[jj];
#pragma unroll
            for (int ni = 0; ni < 4; ++ni)
#pragma unroll
                for (int jj = 0; jj < 4; ++jj) {
                    int r = lh * 4 + jj, j = ni * 16 + l15;
                    *(__bf16*)((char*)Pl[wave] + r * 128 + ((j * 2) ^ ((r & 7) << 4))) =
                        (__bf16)p[ni][jj];
                }
        }
        __syncthreads();   // P write -> P read
        if (act) {
            bf16x8 pf[2];
            pf[0] = *(const bf16x8*)((char*)Pl[wave] + l15 * 128 + ((lh * 16)      ^ ((l15 & 7) << 4)));
            pf[1] = *(const bf16x8*)((char*)Pl[wave] + l15 * 128 + ((64 + lh * 16) ^ ((l15 & 7) << 4)));
#pragma unroll
            for (int dblk = 0; dblk < 4; ++dblk) {
                int dr = dblk * 16 + l15;
                bf16x8 vf0 = *(const bf16x8*)((char*)vT[cid] + dr * 128 + ((lh * 16)      ^ ((dr & 7) << 4)));
                bf16x8 vf1 = *(const bf16x8*)((char*)vT[cid] + dr * 128 + ((64 + lh * 16) ^ ((dr & 7) << 4)));
                oacc[dblk] = __builtin_amdgcn_mfma_f32_16x16x32_bf16(pf[0], vf0, oacc[dblk], 0, 0, 0);
                oacc[dblk] = __builtin_amdgcn_mfma_f32_16x16x32_bf16(pf[1], vf1, oacc[dblk], 0, 0, 0);
            }
        }
    }

    // -------- flash merge of 4 chunk-partials --------
    __syncthreads();
    if (l15 == 0) {
#pragma unroll
        for (int jj = 0; jj < 4; ++jj) {
            mbuf[(cid * 4 + g) * 16 + lh * 4 + jj] = m_s[jj];
            lbuf[(cid * 4 + g) * 16 + lh * 4 + jj] = l_s[jj];
        }
    }
    __syncthreads();
    float sc[4], Lsum[4];
#pragma unroll
    for (int jj = 0; jj < 4; ++jj) {
        int r = lh * 4 + jj;
        float M = mbuf[(0 * 4 + g) * 16 + r];
#pragma unroll
        for (int c = 1; c < 4; ++c) M = fmaxf(M, mbuf[(c * 4 + g) * 16 + r]);
        sc[jj] = __expf(m_s[jj] - M);
        float L = 0.f;
#pragma unroll
        for (int c = 0; c < 4; ++c)
            L += lbuf[(c * 4 + g) * 16 + r] * __expf(mbuf[(c * 4 + g) * 16 + r] - M);
        Lsum[jj] = L;
    }
#pragma unroll
    for (int c = 0; c < 4; ++c) {
        if (cid == c) {
#pragma unroll
            for (int dblk = 0; dblk < 4; ++dblk)
#pragma unroll
                for (int jj = 0; jj < 4; ++jj) {
                    int off = (g * 16 + lh * 4 + jj) * 64 + dblk * 16 + l15;
                    float v = oacc[dblk][jj] * sc[jj];
                    if (c == 0) Osum[off] = v;
                    else        Osum[off] += v;
                }
        }
        __syncthreads();
    }
    if (cid == 0) {
        __bf16* ob = o + ((size_t)bt * 64 + g * 16) * 512 + h * 64;
#pragma unroll
        for (int dblk = 0; dblk < 4; ++dblk)
#pragma unroll
            for (int jj = 0; jj < 4; ++jj) {
                int r = lh * 4 + jj;
                float v = Osum[(g * 16 + r) * 64 + dblk * 16 + l15] / Lsum[jj];
                ob[(size_t)r * 512 + dblk * 16 + l15] = (__bf16)v;
            }
    }
}

// ---------------------------------------------------------------- launch
extern "C" void kernel_launch(void* const* d_in, const int* in_sizes, int n_in,
                              void* d_out, int out_size, void* d_ws, size_t ws_size,
                              hipStream_t stream) {
    const float* x    = (const float*)d_in[0];
    const float* lat  = (const float*)d_in[1];
    const float* g_m  = (const float*)d_in[2];
    const float* b_m  = (const float*)d_in[3];
    const float* g_l  = (const float*)d_in[4];
    const float* b_l  = (const float*)d_in[5];
    const float* Wq   = (const float*)d_in[6];
    const float* Wkv  = (const float*)d_in[7];
    const float* Wout = (const float*)d_in[8];
    float* out = (float*)d_out;

    char* ws = (char*)d_ws;
    __bf16* A_cat = (__bf16*)ws; ws += (size_t)36864 * 1024 * 2;   // LN(concat) + latln
    __bf16* kvq   = (__bf16*)ws; ws += (size_t)36864 * 1024 * 2;   // kv + q
    __bf16* ab    = (__bf16*)ws; ws += (size_t)2048 * 512 * 2;
    __bf16* B_cat = (__bf16*)ws; ws += (size_t)1536 * 1024 * 2;    // WkvT + WqT
    __bf16* WoutT = (__bf16*)ws; ws += (size_t)1024 * 512 * 2;

    __bf16* latln = A_cat + (size_t)34816 * 1024;
    __bf16* WkvT  = B_cat;
    __bf16* WqT   = B_cat + (size_t)1024 * 1024;
    __bf16* qb    = kvq   + (size_t)34816 * 1024;   // rows 34816+, cols [0,512)

    // fused: weight transposes (2048 blocks) | LN (34816 blocks)
    prep_kernel<<<2048 + 34816, 256, 0, stream>>>(
        Wq, Wkv, Wout, WqT, WkvT, WoutT,
        x, lat, g_m, b_m, g_l, b_l, A_cat, latln);

    // uniform fused: kv (2176 blocks) | q (64 blocks, overlapped in tail); runtime K
    qkv_gemm<<<2240, 256, 0, stream>>>(A_cat, B_cat, kvq, 1024);

    attn_kernel<<<256, 1024, 0, stream>>>(qb, kvq, ab);

    // out = attn @ Wout   (M=2048, N=1024, K=512); nwg = 16*8 = 128
    gemm_bf16<false><<<128, 256, 0, stream>>>(ab, WoutT, out, 2048, 1024, 512, 1.0f, 8);
}